// Round 7
// baseline (277.523 us; speedup 1.0000x reference)
//
#include <hip/hip_runtime.h>
#include <hip/hip_bf16.h>

typedef __bf16 bf16_t;
typedef __bf16 bf16x4 __attribute__((ext_vector_type(4)));
typedef __bf16 bf16x8 __attribute__((ext_vector_type(8)));
typedef float f32x4 __attribute__((ext_vector_type(4)));

#define MFMA16(a, b, c) __builtin_amdgcn_mfma_f32_16x16x32_bf16(a, b, c, 0, 0, 0)

// async 16B global->LDS (m97 pattern). lds ptr wave-uniform; lane writes
// ldsbase + lane*16; GLOBAL src is per-lane.
__device__ __forceinline__ void gld16(const bf16_t* g, bf16_t* l) {
  __builtin_amdgcn_global_load_lds(
      (const __attribute__((address_space(1))) unsigned int*)(const void*)g,
      (__attribute__((address_space(3))) unsigned int*)(void*)l, 16, 0, 0);
}

// ---------------------------------------------------------------------------
// f32 -> bf16 elementwise convert (n multiple of 8)
// ---------------------------------------------------------------------------
__global__ __launch_bounds__(256) void cvt_f32_bf16(
    const float* __restrict__ src, bf16_t* __restrict__ dst, long long n) {
  long long i = ((long long)blockIdx.x * 256 + threadIdx.x) * 8;
  const long long stride = (long long)gridDim.x * 256 * 8;
  for (; i < n; i += stride) {
    f32x4 a = *(const f32x4*)(src + i);
    f32x4 b = *(const f32x4*)(src + i + 4);
    bf16x8 r;
#pragma unroll
    for (int e = 0; e < 4; ++e) {
      r[e] = (bf16_t)a[e];
      r[4 + e] = (bf16_t)b[e];
    }
    *(bf16x8*)(dst + i) = r;
  }
}

// ---------------------------------------------------------------------------
// v7: 256x256 8-phase GEMM (m198/m201 structure, plain HIP).
// C[m][n] = sum_k A[m][k]*W[n][k] (+bias). A row-stride lda, W row-stride K.
// 8 waves (2M x 4N), per-wave C = 128x64 (acc[8][4] f32x4). BK=64, NT=K/64.
// LDS: 2 dbuf x (As 256x64 + Bs 256x64) bf16 = 128 KB -> 1 block/CU.
// Per K-tile: 4 phases {12 ds_read(swz) -> 2 gld16 prefetch(t+1, other buf)
//   -> setprio(1) 16 MFMA setprio(0) -> s_barrier}; __syncthreads per K-tile.
// T2 swizzle (both-sides involution, rule #21): linear gld16 dest; SOURCE col
// pre-swizzled: scol = ((l&7)^(l>>3))<<3 ; READ slot = (ks*4+quad)^(row&7).
// Race audit: prefetch touches only buf^1; prior readers of buf^1 passed the
// previous K-tile's __syncthreads (precedes all issue); the end-of-tile
// __syncthreads drains vmcnt/lgkm and publishes. Phase s_barriers carry no
// LDS handoff (scheduling only).
// ---------------------------------------------------------------------------
template <typename TC, bool BIAS>
__global__ __launch_bounds__(512, 2) void gemm256(
    const bf16_t* __restrict__ A, int lda, const bf16_t* __restrict__ W,
    const float* __restrict__ bias, TC* __restrict__ C,
    int M, int N, int K) {
  __shared__ bf16_t As[2][256 * 64];
  __shared__ bf16_t Bs[2][256 * 64];

  const int tid = threadIdx.x;
  const int lane = tid & 63;
  const int w = tid >> 6;       // 0..7
  const int l16 = tid & 15;
  const int quad = (tid >> 4) & 3;
  const int wm = w >> 2;        // 0..1
  const int wn = w & 3;         // 0..3

  // chunked XCD swizzle (bijective: nwg % 8 == 0 for both grids)
  const int gx = gridDim.x;
  const int nwg = gx * gridDim.y;
  int wg = blockIdx.y * gx + blockIdx.x;
  if ((nwg & 7) == 0) wg = (wg & 7) * (nwg >> 3) + (wg >> 3);
  const int m0 = (wg / gx) * 256;
  const int n0 = (wg % gx) * 256;

  // staging source (per-lane): row srow within 8-row group, col pre-swizzled
  const int srow = lane >> 3;                       // 0..7
  const int scol = ((lane & 7) ^ srow) << 3;        // inverse-swizzled elems
  const bf16_t* agbase = A + (size_t)(m0 + srow) * lda + scol;
  const bf16_t* bgbase = W + (size_t)(n0 + srow) * K + scol;

  f32x4 acc[8][4] = {};
  const int NT = K >> 6;

  // stage half-tile q of K-tile kt into buf: q=0/1 -> A rows 0-127/128-255,
  // q=2/3 -> B rows 0-127/128-255. 2 gld16 per thread (8-row groups).
  auto stage = [&](int buf, int kt, int q) {
#pragma unroll
    for (int c = 0; c < 2; ++c) {
      const int rowg = (q & 1) * 128 + (w * 2 + c) * 8;  // tile-local row
      if (q < 2) {
        gld16(agbase + (size_t)rowg * lda + kt * 64, &As[buf][rowg * 64]);
      } else {
        gld16(bgbase + (size_t)rowg * K + kt * 64, &Bs[buf][rowg * 64]);
      }
    }
  };

  // prologue: K-tile 0 fully into buf 0
#pragma unroll
  for (int q = 0; q < 4; ++q) stage(0, 0, q);
  __syncthreads();

  for (int t = 0; t < NT; ++t) {
    const int buf = t & 1;
    const bool pf = (t + 1 < NT);
#pragma unroll
    for (int q = 0; q < 4; ++q) {
      const int rh = q >> 1, ch = q & 1;  // C-quadrant of this wave's 128x64
      bf16x8 af[4][2], bfr[2][2];
#pragma unroll
      for (int mf = 0; mf < 4; ++mf)
#pragma unroll
        for (int ks = 0; ks < 2; ++ks) {
          const int row = wm * 128 + rh * 64 + mf * 16 + l16;
          const int slot = (ks * 4 + quad) ^ (l16 & 7);
          af[mf][ks] = *(const bf16x8*)&As[buf][row * 64 + slot * 8];
        }
#pragma unroll
      for (int nf = 0; nf < 2; ++nf)
#pragma unroll
        for (int ks = 0; ks < 2; ++ks) {
          const int row = wn * 64 + ch * 32 + nf * 16 + l16;
          const int slot = (ks * 4 + quad) ^ (l16 & 7);
          bfr[nf][ks] = *(const bf16x8*)&Bs[buf][row * 64 + slot * 8];
        }
      if (pf) stage(buf ^ 1, t + 1, q);  // one half-tile per phase
      __builtin_amdgcn_s_setprio(1);
#pragma unroll
      for (int mf = 0; mf < 4; ++mf)
#pragma unroll
        for (int nf = 0; nf < 2; ++nf)
#pragma unroll
          for (int ks = 0; ks < 2; ++ks)
            acc[rh * 4 + mf][ch * 2 + nf] =
                MFMA16(af[mf][ks], bfr[nf][ks], acc[rh * 4 + mf][ch * 2 + nf]);
      __builtin_amdgcn_s_setprio(0);
      if (q < 3) __builtin_amdgcn_s_barrier();  // scheduling-only phase sync
    }
    __syncthreads();  // drains vmcnt+lgkm; K-tile t+1 resident & published
  }

#pragma unroll
  for (int nf = 0; nf < 4; ++nf) {
    const int col = n0 + wn * 64 + nf * 16 + l16;
    const float bv = BIAS ? bias[col] : 0.0f;
#pragma unroll
    for (int mf = 0; mf < 8; ++mf) {
      const int row = m0 + wm * 128 + mf * 16 + quad * 4;
#pragma unroll
      for (int r = 0; r < 4; ++r)
        C[(size_t)(row + r) * N + col] = (TC)(acc[mf][nf][r] + bv);
    }
  }
}

// ---------------------------------------------------------------------------
// Fallback GEMM (128x128, r4 config) — used only when ws lacks room for the
// bf16 w_out copy. W f32 via reg-staging (WF32=true).
// ---------------------------------------------------------------------------
template <bool WF32, typename TC, bool BIAS>
__global__ __launch_bounds__(256, 3) void gemm_async(
    const bf16_t* __restrict__ A, int lda, const void* __restrict__ Wv,
    const float* __restrict__ bias, TC* __restrict__ C, int ldc,
    int M, int N, int K) {
  constexpr int BST = WF32 ? 40 : 32;
  __shared__ bf16_t As[2][128 * 32];
  __shared__ bf16_t Bs[2][128 * BST];

  const int tid = threadIdx.x;
  const int i = tid & 63;
  const int w = tid >> 6;
  const int l16 = tid & 15;
  const int quad = (tid >> 4) & 3;
  const int wm = w & 1;
  const int wn = w >> 1;

  const int nwg = gridDim.x * gridDim.y;
  int wg = blockIdx.y * gridDim.x + blockIdx.x;
  if ((nwg & 7) == 0) wg = (wg & 7) * (nwg >> 3) + (wg >> 3);
  const int m0 = (wg / gridDim.x) * 128;
  const int n0 = (wg % gridDim.x) * 128;

  const bf16_t* ag = A + (size_t)(m0 + w * 32 + (i >> 2)) * lda + (i & 3) * 8;
  bf16_t* as0[2] = {&As[0][(w * 32) * 32], &As[1][(w * 32) * 32]};
  bf16_t* as1[2] = {&As[0][(w * 32 + 16) * 32], &As[1][(w * 32 + 16) * 32]};

  const bf16_t* bg = nullptr;
  bf16_t *bs0[2] = {nullptr, nullptr}, *bs1[2] = {nullptr, nullptr};
  const float* wfg = nullptr;
  bf16_t* bsw[2] = {nullptr, nullptr};
  if (!WF32) {
    bg = (const bf16_t*)Wv + (size_t)(n0 + w * 32 + (i >> 2)) * K + (i & 3) * 8;
    bs0[0] = &Bs[0][(w * 32) * 32];
    bs0[1] = &Bs[1][(w * 32) * 32];
    bs1[0] = &Bs[0][(w * 32 + 16) * 32];
    bs1[1] = &Bs[1][(w * 32 + 16) * 32];
  } else {
    const int srow = tid >> 1;
    const int scol = (tid & 1) * 16;
    wfg = (const float*)Wv + (size_t)(n0 + srow) * K + scol;
    bsw[0] = &Bs[0][srow * BST + scol];
    bsw[1] = &Bs[1][srow * BST + scol];
  }

  f32x4 acc[4][4] = {};

  gld16(ag, as0[0]);
  gld16(ag + 16 * lda, as1[0]);
  if (!WF32) {
    gld16(bg, bs0[0]);
    gld16(bg + 16 * K, bs1[0]);
  } else {
    f32x4 a = *(const f32x4*)(wfg);
    f32x4 b = *(const f32x4*)(wfg + 4);
    f32x4 c2 = *(const f32x4*)(wfg + 8);
    f32x4 d = *(const f32x4*)(wfg + 12);
    bf16x8 r0, r1;
#pragma unroll
    for (int e = 0; e < 4; ++e) {
      r0[e] = (bf16_t)a[e];
      r0[4 + e] = (bf16_t)b[e];
      r1[e] = (bf16_t)c2[e];
      r1[4 + e] = (bf16_t)d[e];
    }
    *(bf16x8*)(bsw[0]) = r0;
    *(bf16x8*)(bsw[0] + 8) = r1;
  }
  __syncthreads();

  int cur = 0;
  for (int k0 = 0; k0 < K; k0 += 32) {
    const bool has_next = (k0 + 32 < K);
    const int nxt = cur ^ 1;
    f32x4 wa, wb, wc, wd;

    if (has_next) {
      gld16(ag + k0 + 32, as0[nxt]);
      gld16(ag + 16 * lda + k0 + 32, as1[nxt]);
      if (!WF32) {
        gld16(bg + k0 + 32, bs0[nxt]);
        gld16(bg + 16 * K + k0 + 32, bs1[nxt]);
      } else {
        wa = *(const f32x4*)(wfg + k0 + 32);
        wb = *(const f32x4*)(wfg + k0 + 36);
        wc = *(const f32x4*)(wfg + k0 + 40);
        wd = *(const f32x4*)(wfg + k0 + 44);
      }
    }

    bf16x8 af[4], bfr[4];
#pragma unroll
    for (int t = 0; t < 4; ++t) {
      af[t] = *(const bf16x8*)&As[cur][(wm * 64 + t * 16 + l16) * 32 + quad * 8];
      bfr[t] =
          *(const bf16x8*)&Bs[cur][(wn * 64 + t * 16 + l16) * BST + quad * 8];
    }
    __builtin_amdgcn_s_setprio(1);
#pragma unroll
    for (int mi = 0; mi < 4; ++mi)
#pragma unroll
      for (int ni = 0; ni < 4; ++ni)
        acc[mi][ni] = MFMA16(af[mi], bfr[ni], acc[mi][ni]);
    __builtin_amdgcn_s_setprio(0);

    if (WF32 && has_next) {
      bf16x8 r0, r1;
#pragma unroll
      for (int e = 0; e < 4; ++e) {
        r0[e] = (bf16_t)wa[e];
        r0[4 + e] = (bf16_t)wb[e];
        r1[e] = (bf16_t)wc[e];
        r1[4 + e] = (bf16_t)wd[e];
      }
      *(bf16x8*)(bsw[nxt]) = r0;
      *(bf16x8*)(bsw[nxt] + 8) = r1;
    }

    __syncthreads();
    cur = nxt;
  }

#pragma unroll
  for (int ni = 0; ni < 4; ++ni) {
    const int col = n0 + wn * 64 + ni * 16 + l16;
    const float bv = BIAS ? bias[col] : 0.0f;
#pragma unroll
    for (int mi = 0; mi < 4; ++mi) {
      const int row = m0 + wm * 64 + mi * 16 + quad * 4;
#pragma unroll
      for (int r = 0; r < 4; ++r)
        C[(size_t)(row + r) * ldc + col] = (TC)(acc[mi][ni][r] + bv);
    }
  }
}

// ---------------------------------------------------------------------------
// Flash attention (causal), qkv interleaved [B*T, 3C] bf16 (q|k|v).
// Best measured config (87.6 µs): pairing grid (8, B*H), single-buffer,
// swapped QK^T, exp2-domain softmax, diagonal-only mask, exact defer-skip,
// T14 reg-staged prefetch, setprio. UNCHANGED this round.
// ---------------------------------------------------------------------------
__global__ __launch_bounds__(512, 4) void attn_mfma(bf16_t* __restrict__ qkv) {
  constexpr int T = 2048, C3 = 3072, C = 1024;
  __shared__ bf16_t Ks[64 * 72];      // [token][d], +8 pad
  __shared__ bf16_t Vt[64 * 72];      // [d][token], +8 pad
  __shared__ bf16_t Ps[8 * 16 * 72];  // per-wave P tile [qrow][key]

  const int tid = threadIdx.x;
  const int wave = tid >> 6;        // 0..7
  const int lane = tid & 63;
  const int l16 = tid & 15;
  const int quad = (tid >> 4) & 3;
  const int p = blockIdx.x;         // 0..7 -> strips p and 15-p
  const int b = blockIdx.y >> 4;
  const int h = blockIdx.y & 15;
  bf16_t* base = qkv + (size_t)b * T * C3;

  const float QSCALE = 0.125f * 1.44269504088896340736f;

  const int kst = tid >> 2;
  const int ksd = (tid & 3) * 16;
  const int vtok = lane;
  const int vdg = (wave - 4) * 16;

  bf16_t* pw = &Ps[wave * 16 * 72];

  bf16x8 st0, st1;

  for (int s = 0; s < 2; ++s) {
    const int qt = (s == 0) ? p : 15 - p;
    const int Q0 = qt * 128;
    const int qlo = Q0 + wave * 16;
    const int jmax = Q0 + 64;

    bf16x8 qf[2];
    {
      const bf16_t* qp = base + (size_t)(qlo + l16) * C3 + h * 64 + quad * 8;
      bf16x8 a = *(const bf16x8*)qp;
      bf16x8 c = *(const bf16x8*)(qp + 32);
#pragma unroll
      for (int e = 0; e < 8; ++e) {
        a[e] = (bf16_t)((float)a[e] * QSCALE);
        c[e] = (bf16_t)((float)c[e] * QSCALE);
      }
      qf[0] = a;
      qf[1] = c;
    }

    f32x4 Of[4] = {};
    float mrow = -1e30f;
    float lrow = 0.f;

    if (wave < 4) {
      const bf16_t* kp = base + (size_t)kst * C3 + C + h * 64 + ksd;
      st0 = *(const bf16x8*)kp;
      st1 = *(const bf16x8*)(kp + 8);
    } else {
      const bf16_t* vp = base + (size_t)vtok * C3 + 2 * C + h * 64 + vdg;
      st0 = *(const bf16x8*)vp;
      st1 = *(const bf16x8*)(vp + 8);
    }

    for (int j0 = 0; j0 <= jmax; j0 += 64) {
      __syncthreads();
      if (wave < 4) {
        *(bf16x8*)&Ks[kst * 72 + ksd] = st0;
        *(bf16x8*)&Ks[kst * 72 + ksd + 8] = st1;
      } else {
#pragma unroll
        for (int e = 0; e < 8; ++e) {
          Vt[(vdg + e) * 72 + vtok] = st0[e];
          Vt[(vdg + 8 + e) * 72 + vtok] = st1[e];
        }
      }
      if (j0 + 64 <= jmax) {
        const int jn = j0 + 64;
        if (wave < 4) {
          const bf16_t* kp = base + (size_t)(jn + kst) * C3 + C + h * 64 + ksd;
          st0 = *(const bf16x8*)kp;
          st1 = *(const bf16x8*)(kp + 8);
        } else {
          const bf16_t* vp =
              base + (size_t)(jn + vtok) * C3 + 2 * C + h * 64 + vdg;
          st0 = *(const bf16x8*)vp;
          st1 = *(const bf16x8*)(vp + 8);
        }
      }
      __syncthreads();

      if (qlo + 15 < j0) continue;

      float Sv[4][4];
      const int qrow = qlo + l16;
      __builtin_amdgcn_s_setprio(1);
#pragma unroll
      for (int nt = 0; nt < 4; ++nt) {
        f32x4 sacc = {};
#pragma unroll
        for (int s2 = 0; s2 < 2; ++s2) {
          bf16x8 kf =
              *(const bf16x8*)&Ks[(nt * 16 + l16) * 72 + s2 * 32 + quad * 8];
          sacc = MFMA16(kf, qf[s2], sacc);
        }
#pragma unroll
        for (int r = 0; r < 4; ++r) Sv[nt][r] = sacc[r];
      }
      __builtin_amdgcn_s_setprio(0);

      if (j0 + 64 > qlo) {
#pragma unroll
        for (int nt = 0; nt < 4; ++nt) {
          const int keyb = j0 + nt * 16 + quad * 4;
#pragma unroll
          for (int r = 0; r < 4; ++r)
            if (keyb + r > qrow) Sv[nt][r] = -1e30f;
        }
      }

      float vm[4];
#pragma unroll
      for (int nt = 0; nt < 4; ++nt)
        vm[nt] = fmaxf(fmaxf(Sv[nt][0], Sv[nt][1]),
                       fmaxf(Sv[nt][2], Sv[nt][3]));
      float v = fmaxf(fmaxf(vm[0], vm[1]), fmaxf(vm[2], vm[3]));
      v = fmaxf(v, __shfl_xor(v, 16));
      v = fmaxf(v, __shfl_xor(v, 32));

      if (__any(v > mrow)) {
        const float mnew = fmaxf(mrow, v);
        const float alpha = __builtin_amdgcn_exp2f(mrow - mnew);
        mrow = mnew;
        lrow *= alpha;
        float ar[4];
#pragma unroll
        for (int r = 0; r < 4; ++r) ar[r] = __shfl(alpha, quad * 4 + r, 16);
#pragma unroll
        for (int dt = 0; dt < 4; ++dt)
#pragma unroll
          for (int r = 0; r < 4; ++r) Of[dt][r] *= ar[r];
      }

      float rsn[4];
#pragma unroll
      for (int nt = 0; nt < 4; ++nt) {
        bf16x4 pk;
        float r0 = __builtin_amdgcn_exp2f(Sv[nt][0] - mrow);
        float r1 = __builtin_amdgcn_exp2f(Sv[nt][1] - mrow);
        float r2 = __builtin_amdgcn_exp2f(Sv[nt][2] - mrow);
        float r3 = __builtin_amdgcn_exp2f(Sv[nt][3] - mrow);
        pk[0] = (bf16_t)r0;
        pk[1] = (bf16_t)r1;
        pk[2] = (bf16_t)r2;
        pk[3] = (bf16_t)r3;
        rsn[nt] = (r0 + r1) + (r2 + r3);
        *(bf16x4*)&pw[l16 * 72 + nt * 16 + quad * 4] = pk;
      }
      float rs = (rsn[0] + rsn[1]) + (rsn[2] + rsn[3]);
      rs += __shfl_xor(rs, 16);
      rs += __shfl_xor(rs, 32);
      lrow += rs;

      bf16x8 pf0 = *(const bf16x8*)&pw[l16 * 72 + quad * 8];
      bf16x8 pf1 = *(const bf16x8*)&pw[l16 * 72 + 32 + quad * 8];
      __builtin_amdgcn_s_setprio(1);
#pragma unroll
      for (int dt = 0; dt < 4; ++dt) {
        bf16x8 vf0 = *(const bf16x8*)&Vt[(dt * 16 + l16) * 72 + quad * 8];
        bf16x8 vf1 = *(const bf16x8*)&Vt[(dt * 16 + l16) * 72 + 32 + quad * 8];
        Of[dt] = MFMA16(pf0, vf0, Of[dt]);
        Of[dt] = MFMA16(pf1, vf1, Of[dt]);
      }
      __builtin_amdgcn_s_setprio(0);
    }

    float lr[4];
#pragma unroll
    for (int r = 0; r < 4; ++r) lr[r] = __shfl(lrow, quad * 4 + r, 16);
    const int t = Q0 + wave * 16 + quad * 4;
#pragma unroll
    for (int r = 0; r < 4; ++r) {
      const float inv = 1.0f / lr[r];
      bf16_t* op = base + (size_t)(t + r) * C3 + h * 64 + l16;
#pragma unroll
      for (int dt = 0; dt < 4; ++dt)
        op[dt * 16] = (bf16_t)(Of[dt][r] * inv);
    }
  }
}

// ---------------------------------------------------------------------------
// I/O contract (R8 probe): ALL inputs f32; output f32.
// ---------------------------------------------------------------------------
extern "C" void kernel_launch(void* const* d_in, const int* in_sizes, int n_in,
                              void* d_out, int out_size, void* d_ws,
                              size_t ws_size, hipStream_t stream) {
  constexpr int B = 4, T = 2048, C = 1024;
  constexpr int M = B * T;  // 8192

  const float* x = (const float*)d_in[0];
  const float* w_qkv = (const float*)d_in[1];
  const float* w_out = (const float*)d_in[2];
  const float* b_out = (const float*)d_in[3];
  for (int i = 0; i < n_in; ++i) {
    const long long s = in_sizes[i];
    if (s == (long long)M * C) x = (const float*)d_in[i];
    else if (s == (long long)3 * C * C) w_qkv = (const float*)d_in[i];
    else if (s == (long long)C * C) w_out = (const float*)d_in[i];
    else if (s == C) b_out = (const float*)d_in[i];
  }

  bf16_t* xb = (bf16_t*)d_out;                    // 16 MB
  bf16_t* wqb = xb + (size_t)M * C;               // 6 MB
  bf16_t* qkv = (bf16_t*)d_ws;                    // 48 MB
  bf16_t* wob = qkv + (size_t)M * 3 * C;          // +2 MB (guarded)
  const bool ws_ok =
      ws_size >= (size_t)M * 3 * C * 2 + (size_t)C * C * 2;

  cvt_f32_bf16<<<1024, 256, 0, stream>>>(x, xb, (long long)M * C);
  cvt_f32_bf16<<<512, 256, 0, stream>>>(w_qkv, wqb, 3LL * C * C);
  if (ws_ok)
    cvt_f32_bf16<<<256, 256, 0, stream>>>(w_out, wob, (long long)C * C);

  // fused QKV: [M,3C] = xb @ wqb^T  (256^2 8-phase)
  gemm256<bf16_t, false><<<dim3(3 * C / 256, M / 256), 512, 0, stream>>>(
      xb, C, wqb, nullptr, qkv, M, 3 * C, C);

  // attention in place (Q slot of qkv); work-balanced pairing grid
  attn_mfma<<<dim3(8, B * 16), 512, 0, stream>>>(qkv);

  // out = att @ w_out^T + b_out -> f32 d_out
  if (ws_ok)
    gemm256<float, true><<<dim3(C / 256, M / 256), 512, 0, stream>>>(
        qkv, 3 * C, wob, b_out, (float*)d_out, M, C, C);
  else
    gemm_async<true, float, true><<<dim3(C / 128, M / 128), 256, 0, stream>>>(
        qkv, 3 * C, w_out, b_out, (float*)d_out, C, M, C, C);
}

// Round 8
// 258.398 us; speedup vs baseline: 1.0740x; 1.0740x over previous
//
#include <hip/hip_runtime.h>
#include <hip/hip_bf16.h>

typedef __bf16 bf16_t;
typedef __bf16 bf16x4 __attribute__((ext_vector_type(4)));
typedef __bf16 bf16x8 __attribute__((ext_vector_type(8)));
typedef float f32x4 __attribute__((ext_vector_type(4)));

#define MFMA16(a, b, c) __builtin_amdgcn_mfma_f32_16x16x32_bf16(a, b, c, 0, 0, 0)

// async 16B global->LDS (m97 pattern). lds ptr wave-uniform; lane writes
// ldsbase + lane*16.
__device__ __forceinline__ void gld16(const bf16_t* g, bf16_t* l) {
  __builtin_amdgcn_global_load_lds(
      (const __attribute__((address_space(1))) unsigned int*)(const void*)g,
      (__attribute__((address_space(3))) unsigned int*)(void*)l, 16, 0, 0);
}

// ---------------------------------------------------------------------------
// f32 -> bf16 elementwise convert (n multiple of 8)
// ---------------------------------------------------------------------------
__global__ __launch_bounds__(256) void cvt_f32_bf16(
    const float* __restrict__ src, bf16_t* __restrict__ dst, long long n) {
  long long i = ((long long)blockIdx.x * 256 + threadIdx.x) * 8;
  const long long stride = (long long)gridDim.x * 256 * 8;
  for (; i < n; i += stride) {
    f32x4 a = *(const f32x4*)(src + i);
    f32x4 b = *(const f32x4*)(src + i + 4);
    bf16x8 r;
#pragma unroll
    for (int e = 0; e < 4; ++e) {
      r[e] = (bf16_t)a[e];
      r[4 + e] = (bf16_t)b[e];
    }
    *(bf16x8*)(dst + i) = r;
  }
}

// ---------------------------------------------------------------------------
// GEMM (r4 config — best measured, GEMM-side ~165 µs total):
// C[m][n] = sum_k A[m][k]*W[n][k] (+bias). A bf16 via global_load_lds.
// 128x128 tile, 4 waves (2x2), 64x64/wave, BK=32, 2-phase double-buffer,
// __launch_bounds__(256,3), chunked XCD swizzle. The 256^2 8-phase port
// (r7) regressed (+17 µs) — reverted.
// ---------------------------------------------------------------------------
template <bool WF32, typename TC, bool BIAS>
__global__ __launch_bounds__(256, 3) void gemm_async(
    const bf16_t* __restrict__ A, int lda, const void* __restrict__ Wv,
    const float* __restrict__ bias, TC* __restrict__ C, int ldc,
    int M, int N, int K) {
  constexpr int BST = WF32 ? 40 : 32;
  __shared__ bf16_t As[2][128 * 32];
  __shared__ bf16_t Bs[2][128 * BST];

  const int tid = threadIdx.x;
  const int i = tid & 63;
  const int w = tid >> 6;
  const int l16 = tid & 15;
  const int quad = (tid >> 4) & 3;
  const int wm = w & 1;
  const int wn = w >> 1;

  const int nwg = gridDim.x * gridDim.y;
  int wg = blockIdx.y * gridDim.x + blockIdx.x;
  if ((nwg & 7) == 0) wg = (wg & 7) * (nwg >> 3) + (wg >> 3);
  const int m0 = (wg / gridDim.x) * 128;
  const int n0 = (wg % gridDim.x) * 128;

  const bf16_t* ag = A + (size_t)(m0 + w * 32 + (i >> 2)) * lda + (i & 3) * 8;
  bf16_t* as0[2] = {&As[0][(w * 32) * 32], &As[1][(w * 32) * 32]};
  bf16_t* as1[2] = {&As[0][(w * 32 + 16) * 32], &As[1][(w * 32 + 16) * 32]};

  const bf16_t* bg = nullptr;
  bf16_t *bs0[2] = {nullptr, nullptr}, *bs1[2] = {nullptr, nullptr};
  const float* wfg = nullptr;
  bf16_t* bsw[2] = {nullptr, nullptr};
  if (!WF32) {
    bg = (const bf16_t*)Wv + (size_t)(n0 + w * 32 + (i >> 2)) * K + (i & 3) * 8;
    bs0[0] = &Bs[0][(w * 32) * 32];
    bs0[1] = &Bs[1][(w * 32) * 32];
    bs1[0] = &Bs[0][(w * 32 + 16) * 32];
    bs1[1] = &Bs[1][(w * 32 + 16) * 32];
  } else {
    const int srow = tid >> 1;
    const int scol = (tid & 1) * 16;
    wfg = (const float*)Wv + (size_t)(n0 + srow) * K + scol;
    bsw[0] = &Bs[0][srow * BST + scol];
    bsw[1] = &Bs[1][srow * BST + scol];
  }

  f32x4 acc[4][4] = {};

  gld16(ag, as0[0]);
  gld16(ag + 16 * lda, as1[0]);
  if (!WF32) {
    gld16(bg, bs0[0]);
    gld16(bg + 16 * K, bs1[0]);
  } else {
    f32x4 a = *(const f32x4*)(wfg);
    f32x4 b = *(const f32x4*)(wfg + 4);
    f32x4 c2 = *(const f32x4*)(wfg + 8);
    f32x4 d = *(const f32x4*)(wfg + 12);
    bf16x8 r0, r1;
#pragma unroll
    for (int e = 0; e < 4; ++e) {
      r0[e] = (bf16_t)a[e];
      r0[4 + e] = (bf16_t)b[e];
      r1[e] = (bf16_t)c2[e];
      r1[4 + e] = (bf16_t)d[e];
    }
    *(bf16x8*)(bsw[0]) = r0;
    *(bf16x8*)(bsw[0] + 8) = r1;
  }
  __syncthreads();

  int cur = 0;
  for (int k0 = 0; k0 < K; k0 += 32) {
    const bool has_next = (k0 + 32 < K);
    const int nxt = cur ^ 1;
    f32x4 wa, wb, wc, wd;

    if (has_next) {
      gld16(ag + k0 + 32, as0[nxt]);
      gld16(ag + 16 * lda + k0 + 32, as1[nxt]);
      if (!WF32) {
        gld16(bg + k0 + 32, bs0[nxt]);
        gld16(bg + 16 * K + k0 + 32, bs1[nxt]);
      } else {
        wa = *(const f32x4*)(wfg + k0 + 32);
        wb = *(const f32x4*)(wfg + k0 + 36);
        wc = *(const f32x4*)(wfg + k0 + 40);
        wd = *(const f32x4*)(wfg + k0 + 44);
      }
    }

    bf16x8 af[4], bfr[4];
#pragma unroll
    for (int t = 0; t < 4; ++t) {
      af[t] = *(const bf16x8*)&As[cur][(wm * 64 + t * 16 + l16) * 32 + quad * 8];
      bfr[t] =
          *(const bf16x8*)&Bs[cur][(wn * 64 + t * 16 + l16) * BST + quad * 8];
    }
    __builtin_amdgcn_s_setprio(1);
#pragma unroll
    for (int mi = 0; mi < 4; ++mi)
#pragma unroll
      for (int ni = 0; ni < 4; ++ni)
        acc[mi][ni] = MFMA16(af[mi], bfr[ni], acc[mi][ni]);
    __builtin_amdgcn_s_setprio(0);

    if (WF32 && has_next) {
      bf16x8 r0, r1;
#pragma unroll
      for (int e = 0; e < 4; ++e) {
        r0[e] = (bf16_t)wa[e];
        r0[4 + e] = (bf16_t)wb[e];
        r1[e] = (bf16_t)wc[e];
        r1[4 + e] = (bf16_t)wd[e];
      }
      *(bf16x8*)(bsw[nxt]) = r0;
      *(bf16x8*)(bsw[nxt] + 8) = r1;
    }

    __syncthreads();
    cur = nxt;
  }

#pragma unroll
  for (int ni = 0; ni < 4; ++ni) {
    const int col = n0 + wn * 64 + ni * 16 + l16;
    const float bv = BIAS ? bias[col] : 0.0f;
#pragma unroll
    for (int mi = 0; mi < 4; ++mi) {
      const int row = m0 + wm * 64 + mi * 16 + quad * 4;
#pragma unroll
      for (int r = 0; r < 4; ++r)
        C[(size_t)(row + r) * ldc + col] = (TC)(acc[mi][ni][r] + bv);
    }
  }
}

// ---------------------------------------------------------------------------
// Flash attention (causal), qkv interleaved [B*T, 3C] bf16 (q|k|v).
// Output overwrites the Q slot in place.
//
// v6 (this round): KVBLK 64 -> 128. attn was pinned at ~87-89 µs across six
// configs with no pipe saturated -> cost is the per-tile serial convoy
// (2 barriers + shuffle-reduce + exp + P roundtrip per 64 keys). KVBLK=128
// halves convoys/key: 34 -> 17 tiles per block-pair, half the barriers and
// reductions, double the independent MFMA per chain.
//   LDS: Ks[128*72] + Vt[64*136] + Ps[8*16*136] = 69 KB -> 2 blocks/CU.
//   Strides 72/136 keep byte-residue (=16 mod 128) of the proven layouts.
//   Diagonal tile: wave-uniform ntlim = w+1 skips dead QK^T sub-tiles
//   (exact triangle); dead nt get Sv=-1e30 -> P=exp2(-inf)=0 (PV boundary
//   ks-group reads them); per-element mask only on diagonal tile.
//   PV skips fully-dead ks-groups wave-uniformly (kslim).
// Pairing grid (8, B*H): (p+1)+(16-p) = 17 tiles/block, uniform.
// ---------------------------------------------------------------------------
__global__ __launch_bounds__(512, 4) void attn_mfma(bf16_t* __restrict__ qkv) {
  constexpr int T = 2048, C3 = 3072, C = 1024;
  __shared__ bf16_t Ks[128 * 72];      // [token][d], +8 pad
  __shared__ bf16_t Vt[64 * 136];      // [d][token], +8 pad
  __shared__ bf16_t Ps[8 * 16 * 136];  // per-wave P tile [qrow][key]

  const int tid = threadIdx.x;
  const int wave = tid >> 6;        // 0..7
  const int lane = tid & 63;
  const int l16 = tid & 15;
  const int quad = (tid >> 4) & 3;
  const int p = blockIdx.x;         // 0..7 -> strips p and 15-p
  const int b = blockIdx.y >> 4;
  const int h = blockIdx.y & 15;
  bf16_t* base = qkv + (size_t)b * T * C3;

  // 1/sqrt(64) * log2(e): softmax entirely in exp2 domain.
  const float QSCALE = 0.125f * 1.44269504088896340736f;

  // K staging (waves 0-3): row = wave*32 + (lane>>1), d's (lane&1)*32..+31
  const int krow = wave * 32 + (lane >> 1);
  const int kcol = (lane & 1) * 32;
  // V staging (waves 4-7): wv=wave-4; token = ((wv&2)?64:0)+lane, d0=(wv&1)*32
  const int wv = wave - 4;
  const int vtok = ((wv & 2) << 5) + lane;
  const int vd0 = (wv & 1) * 32;

  bf16_t* pw = &Ps[wave * 16 * 136];

  bf16x8 st0, st1, st2, st3;  // staging regs (K halves or V halves)

  for (int s = 0; s < 2; ++s) {
    const int qt = (s == 0) ? p : 15 - p;
    const int Q0 = qt * 128;
    const int qlo = Q0 + wave * 16;

    // Q fragments, prescaled by 0.125*log2e
    bf16x8 qf[2];
    {
      const bf16_t* qp = base + (size_t)(qlo + l16) * C3 + h * 64 + quad * 8;
      bf16x8 a = *(const bf16x8*)qp;
      bf16x8 c = *(const bf16x8*)(qp + 32);
#pragma unroll
      for (int e = 0; e < 8; ++e) {
        a[e] = (bf16_t)((float)a[e] * QSCALE);
        c[e] = (bf16_t)((float)c[e] * QSCALE);
      }
      qf[0] = a;
      qf[1] = c;
    }

    f32x4 Of[4] = {};
    float mrow = -1e30f;
    float lrow = 0.f;

    // prologue: issue tile-0 loads into regs (T14 split)
    if (wave < 4) {
      const bf16_t* kp = base + (size_t)krow * C3 + C + h * 64 + kcol;
      st0 = *(const bf16x8*)kp;
      st1 = *(const bf16x8*)(kp + 8);
      st2 = *(const bf16x8*)(kp + 16);
      st3 = *(const bf16x8*)(kp + 24);
    } else {
      const bf16_t* vp = base + (size_t)vtok * C3 + 2 * C + h * 64 + vd0;
      st0 = *(const bf16x8*)vp;
      st1 = *(const bf16x8*)(vp + 8);
      st2 = *(const bf16x8*)(vp + 16);
      st3 = *(const bf16x8*)(vp + 24);
    }

    for (int j0 = 0; j0 <= Q0; j0 += 128) {
      __syncthreads();  // previous tile's Ks/Vt readers are done
      // commit staged regs -> LDS (implicit vmcnt wait)
      if (wave < 4) {
        *(bf16x8*)&Ks[krow * 72 + kcol] = st0;
        *(bf16x8*)&Ks[krow * 72 + kcol + 8] = st1;
        *(bf16x8*)&Ks[krow * 72 + kcol + 16] = st2;
        *(bf16x8*)&Ks[krow * 72 + kcol + 24] = st3;
      } else {
#pragma unroll
        for (int e = 0; e < 8; ++e) {
          Vt[(vd0 + e) * 136 + vtok] = st0[e];
          Vt[(vd0 + 8 + e) * 136 + vtok] = st1[e];
          Vt[(vd0 + 16 + e) * 136 + vtok] = st2[e];
          Vt[(vd0 + 24 + e) * 136 + vtok] = st3[e];
        }
      }
      // issue next tile's loads; latency hides under compute below
      if (j0 + 128 <= Q0) {
        const int jn = j0 + 128;
        if (wave < 4) {
          const bf16_t* kp =
              base + (size_t)(jn + krow) * C3 + C + h * 64 + kcol;
          st0 = *(const bf16x8*)kp;
          st1 = *(const bf16x8*)(kp + 8);
          st2 = *(const bf16x8*)(kp + 16);
          st3 = *(const bf16x8*)(kp + 24);
        } else {
          const bf16_t* vp =
              base + (size_t)(jn + vtok) * C3 + 2 * C + h * 64 + vd0;
          st0 = *(const bf16x8*)vp;
          st1 = *(const bf16x8*)(vp + 8);
          st2 = *(const bf16x8*)(vp + 16);
          st3 = *(const bf16x8*)(vp + 24);
        }
      }
      __syncthreads();

      // S^T tile: lane holds S[qlo+l16][j0 + nt*16 + quad*4 + r], nt 0..7
      float Sv[8][4];
      int ntlim = 8;
      if (j0 + 128 <= qlo) {  // full tile: no mask, all 8 nt live
        __builtin_amdgcn_s_setprio(1);
#pragma unroll
        for (int nt = 0; nt < 8; ++nt) {
          f32x4 sacc = {};
#pragma unroll
          for (int s2 = 0; s2 < 2; ++s2) {
            bf16x8 kf = *(const bf16x8*)&Ks[(nt * 16 + l16) * 72 + s2 * 32 +
                                            quad * 8];
            sacc = MFMA16(kf, qf[s2], sacc);
          }
#pragma unroll
          for (int r = 0; r < 4; ++r) Sv[nt][r] = sacc[r];
        }
        __builtin_amdgcn_s_setprio(0);
      } else {  // diagonal tile: wave-uniform ntlim + per-element mask
        ntlim = ((qlo + 15 - j0) >> 4) + 1;  // = wave+1 here
        const int qrow = qlo + l16;
        __builtin_amdgcn_s_setprio(1);
#pragma unroll
        for (int nt = 0; nt < 8; ++nt) {
          if (nt < ntlim) {
            f32x4 sacc = {};
#pragma unroll
            for (int s2 = 0; s2 < 2; ++s2) {
              bf16x8 kf = *(const bf16x8*)&Ks[(nt * 16 + l16) * 72 + s2 * 32 +
                                              quad * 8];
              sacc = MFMA16(kf, qf[s2], sacc);
            }
            const int keyb = j0 + nt * 16 + quad * 4;
#pragma unroll
            for (int r = 0; r < 4; ++r)
              Sv[nt][r] = (keyb + r > qrow) ? -1e30f : sacc[r];
          } else {
#pragma unroll
            for (int r = 0; r < 4; ++r) Sv[nt][r] = -1e30f;
          }
        }
        __builtin_amdgcn_s_setprio(0);
      }

      // tile max for this lane's row (in-lane tree, then cross-quad)
      float v = -1e30f;
#pragma unroll
      for (int nt = 0; nt < 8; ++nt)
        v = fmaxf(v, fmaxf(fmaxf(Sv[nt][0], Sv[nt][1]),
                           fmaxf(Sv[nt][2], Sv[nt][3])));
      v = fmaxf(v, __shfl_xor(v, 16));
      v = fmaxf(v, __shfl_xor(v, 32));

      // exact defer-skip: when no row grew, alpha==1 exactly -> skip rescale
      if (__any(v > mrow)) {
        const float mnew = fmaxf(mrow, v);
        const float alpha = __builtin_amdgcn_exp2f(mrow - mnew);
        mrow = mnew;
        lrow *= alpha;
        float ar[4];
#pragma unroll
        for (int r = 0; r < 4; ++r) ar[r] = __shfl(alpha, quad * 4 + r, 16);
#pragma unroll
        for (int dt = 0; dt < 4; ++dt)
#pragma unroll
          for (int r = 0; r < 4; ++r) Of[dt][r] *= ar[r];
      }

      // P = exp2(S - m); dead nt -> 0. One ds_write_b64 per nt.
      float rs = 0.f;
#pragma unroll
      for (int nt = 0; nt < 8; ++nt) {
        bf16x4 pk;
        float r0 = __builtin_amdgcn_exp2f(Sv[nt][0] - mrow);
        float r1 = __builtin_amdgcn_exp2f(Sv[nt][1] - mrow);
        float r2 = __builtin_amdgcn_exp2f(Sv[nt][2] - mrow);
        float r3 = __builtin_amdgcn_exp2f(Sv[nt][3] - mrow);
        pk[0] = (bf16_t)r0;
        pk[1] = (bf16_t)r1;
        pk[2] = (bf16_t)r2;
        pk[3] = (bf16_t)r3;
        rs += (r0 + r1) + (r2 + r3);
        *(bf16x4*)&pw[l16 * 136 + nt * 16 + quad * 4] = pk;
      }
      rs += __shfl_xor(rs, 16);
      rs += __shfl_xor(rs, 32);
      lrow += rs;

      // PV: skip fully-dead ks-groups (wave-uniform)
      const int kslim = (ntlim + 1) >> 1;
      bf16x8 pf[4];
#pragma unroll
      for (int ks = 0; ks < 4; ++ks)
        pf[ks] = *(const bf16x8*)&pw[l16 * 136 + ks * 32 + quad * 8];
      __builtin_amdgcn_s_setprio(1);
#pragma unroll
      for (int ks = 0; ks < 4; ++ks) {
        if (ks < kslim) {
#pragma unroll
          for (int dt = 0; dt < 4; ++dt) {
            bf16x8 vf = *(const bf16x8*)&Vt[(dt * 16 + l16) * 136 + ks * 32 +
                                            quad * 8];
            Of[dt] = MFMA16(pf[ks], vf, Of[dt]);
          }
        }
      }
      __builtin_amdgcn_s_setprio(0);
    }

    // epilogue: broadcast l to row domain, write O over this wave's Q rows
    float lr[4];
#pragma unroll
    for (int r = 0; r < 4; ++r) lr[r] = __shfl(lrow, quad * 4 + r, 16);
    const int t = Q0 + wave * 16 + quad * 4;
#pragma unroll
    for (int r = 0; r < 4; ++r) {
      const float inv = 1.0f / lr[r];
      bf16_t* op = base + (size_t)(t + r) * C3 + h * 64 + l16;
#pragma unroll
      for (int dt = 0; dt < 4; ++dt)
        op[dt * 16] = (bf16_t)(Of[dt][r] * inv);
    }
  }
}

// ---------------------------------------------------------------------------
// I/O contract (R8 probe): ALL inputs f32; output f32.
// ---------------------------------------------------------------------------
extern "C" void kernel_launch(void* const* d_in, const int* in_sizes, int n_in,
                              void* d_out, int out_size, void* d_ws,
                              size_t ws_size, hipStream_t stream) {
  constexpr int B = 4, T = 2048, C = 1024;
  constexpr int M = B * T;  // 8192

  const float* x = (const float*)d_in[0];
  const float* w_qkv = (const float*)d_in[1];
  const float* w_out = (const float*)d_in[2];
  const float* b_out = (const float*)d_in[3];
  for (int i = 0; i < n_in; ++i) {
    const long long s = in_sizes[i];
    if (s == (long long)M * C) x = (const float*)d_in[i];
    else if (s == (long long)3 * C * C) w_qkv = (const float*)d_in[i];
    else if (s == (long long)C * C) w_out = (const float*)d_in[i];
    else if (s == C) b_out = (const float*)d_in[i];
  }

  bf16_t* xb = (bf16_t*)d_out;                    // 16 MB
  bf16_t* wqb = xb + (size_t)M * C;               // 6 MB
  bf16_t* qkv = (bf16_t*)d_ws;                    // 48 MB
  bf16_t* wob = qkv + (size_t)M * 3 * C;          // +2 MB (guarded)
  const bool ws_ok =
      ws_size >= (size_t)M * 3 * C * 2 + (size_t)C * C * 2;

  cvt_f32_bf16<<<1024, 256, 0, stream>>>(x, xb, (long long)M * C);
  cvt_f32_bf16<<<512, 256, 0, stream>>>(w_qkv, wqb, 3LL * C * C);
  if (ws_ok)
    cvt_f32_bf16<<<256, 256, 0, stream>>>(w_out, wob, (long long)C * C);

  // fused QKV: [M,3C] = xb @ wqb^T
  gemm_async<false, bf16_t, false>
      <<<dim3(3 * C / 128, M / 128), 256, 0, stream>>>(
          xb, C, wqb, nullptr, qkv, 3 * C, M, 3 * C, C);

  // attention in place (Q slot of qkv); work-balanced pairing grid
  attn_mfma<<<dim3(8, B * 16), 512, 0, stream>>>(qkv);

  // out = att @ w_out^T + b_out -> f32 d_out
  if (ws_ok)
    gemm_async<false, float, true><<<dim3(C / 128, M / 128), 256, 0, stream>>>(
        qkv, 3 * C, wob, b_out, (float*)d_out, C, M, C, C);
  else
    gemm_async<true, float, true><<<dim3(C / 128, M / 128), 256, 0, stream>>>(
        qkv, 3 * C, w_out, b_out, (float*)d_out, C, M, C, C);
}

// Round 9
// 243.731 us; speedup vs baseline: 1.1386x; 1.0602x over previous
//
#include <hip/hip_runtime.h>
#include <hip/hip_bf16.h>

typedef __bf16 bf16_t;
typedef __bf16 bf16x4 __attribute__((ext_vector_type(4)));
typedef __bf16 bf16x8 __attribute__((ext_vector_type(8)));
typedef float f32x4 __attribute__((ext_vector_type(4)));

#define MFMA16(a, b, c) __builtin_amdgcn_mfma_f32_16x16x32_bf16(a, b, c, 0, 0, 0)

// async 16B global->LDS (m97 pattern). lds ptr wave-uniform; lane writes
// ldsbase + lane*16; GLOBAL src is per-lane (enables pre-swizzled source).
__device__ __forceinline__ void gld16(const bf16_t* g, bf16_t* l) {
  __builtin_amdgcn_global_load_lds(
      (const __attribute__((address_space(1))) unsigned int*)(const void*)g,
      (__attribute__((address_space(3))) unsigned int*)(void*)l, 16, 0, 0);
}

// ---------------------------------------------------------------------------
// merged f32 -> bf16 convert for all three tensors (one launch, fewer gaps)
// ---------------------------------------------------------------------------
__global__ __launch_bounds__(256) void cvt3_f32_bf16(
    const float* __restrict__ s0, bf16_t* __restrict__ d0, long long n0,
    const float* __restrict__ s1, bf16_t* __restrict__ d1, long long n1,
    const float* __restrict__ s2, bf16_t* __restrict__ d2, long long n2) {
  const long long t0 = ((long long)blockIdx.x * 256 + threadIdx.x) * 8;
  const long long stride = (long long)gridDim.x * 256 * 8;
#pragma unroll 1
  for (int seg = 0; seg < 3; ++seg) {
    const float* s = (seg == 0) ? s0 : (seg == 1) ? s1 : s2;
    bf16_t* d = (seg == 0) ? d0 : (seg == 1) ? d1 : d2;
    const long long n = (seg == 0) ? n0 : (seg == 1) ? n1 : n2;
    if (!d) continue;
    for (long long i = t0; i < n; i += stride) {
      f32x4 a = *(const f32x4*)(s + i);
      f32x4 b = *(const f32x4*)(s + i + 4);
      bf16x8 r;
#pragma unroll
      for (int e = 0; e < 4; ++e) {
        r[e] = (bf16_t)a[e];
        r[4 + e] = (bf16_t)b[e];
      }
      *(bf16x8*)(d + i) = r;
    }
  }
}

// ---------------------------------------------------------------------------
// GEMM v8: 128x128 tile, 4 waves (2x2), 64x64/wave, BK=64 single-buffer.
// C[m][n] = sum_k A[m][k]*W[n][k] (+bias).
//
// Changes vs r4 (BK=32 dbuf):
//  * BK=64 -> HALF the barriers and vmcnt(0) drains per unit K (the
//    documented dominant overhead of this structure). LDS 32 KB single
//    buffer (keeps 3 blocks/CU; avoids m132's 64 KB dbuf cliff).
//  * T2 swizzle via pre-swizzled GLOBAL source + swizzled read (rule #21,
//    involution; index math device-verified by r7's passing gemm256):
//    LDS[row][slot] holds global k-slot (slot ^ (row&7)); read slot' =
//    (ks*4+quad) ^ (l16&7). Frag ds_read_b128 drops from 8/16-way bank
//    conflict to 2-way (free). gld16 dest stays linear (required).
//  * Chunked XCD swizzle kept (r4/r6 best).
// WF32 fallback (w_out f32, used only if ws lacks bf16 copy space):
// reg-stage B with the SAME swizzled layout via ds_write_b128.
// ---------------------------------------------------------------------------
template <bool WF32, typename TC, bool BIAS>
__global__ __launch_bounds__(256, 3) void gemm_async(
    const bf16_t* __restrict__ A, int lda, const void* __restrict__ Wv,
    const float* __restrict__ bias, TC* __restrict__ C, int ldc,
    int M, int N, int K) {
  __shared__ bf16_t As[128 * 64];
  __shared__ bf16_t Bs[128 * 64];

  const int tid = threadIdx.x;
  const int i = tid & 63;
  const int w = tid >> 6;
  const int l16 = tid & 15;
  const int quad = (tid >> 4) & 3;
  const int wm = w & 1;
  const int wn = w >> 1;

  // chunked XCD swizzle (bijective: nwg % 8 == 0 for both grids)
  const int nwg = gridDim.x * gridDim.y;
  int wg = blockIdx.y * gridDim.x + blockIdx.x;
  if ((nwg & 7) == 0) wg = (wg & 7) * (nwg >> 3) + (wg >> 3);
  const int m0 = (wg / gridDim.x) * 128;
  const int n0 = (wg % gridDim.x) * 128;

  // staging: lane i covers row (i>>3) of an 8-row group, k-slot (i&7),
  // source col pre-swizzled by the row's low 3 bits (= i>>3).
  const int srw = i >> 3;                       // 0..7
  const int ssl = ((i & 7) ^ srw) << 3;         // swizzled k-elem offset
  const bf16_t* ag = A + (size_t)(m0 + w * 32 + srw) * lda + ssl;

  const bf16_t* bg = nullptr;
  const float* wfg = nullptr;
  int bsrow = 0, bchunk = 0;
  if (!WF32) {
    bg = (const bf16_t*)Wv + (size_t)(n0 + w * 32 + srw) * K + ssl;
  } else {
    bsrow = tid >> 1;                 // 0..127
    bchunk = tid & 1;                 // k-slots 4*bchunk .. +3
    wfg = (const float*)Wv + (size_t)(n0 + bsrow) * K + bchunk * 32;
  }

  f32x4 acc[4][4] = {};

  for (int kt = 0; kt < (K >> 6); ++kt) {
    if (kt) __syncthreads();  // prev frag reads done before overwrite
    // stage K-tile kt (A: 4 gld16/wave; B: 4 gld16/wave or WF32 reg path)
#pragma unroll
    for (int g = 0; g < 4; ++g)
      gld16(ag + (size_t)(g * 8) * lda + kt * 64, &As[(w * 32 + g * 8) * 64]);
    if (!WF32) {
#pragma unroll
      for (int g = 0; g < 4; ++g)
        gld16(bg + (size_t)(g * 8) * K + kt * 64, &Bs[(w * 32 + g * 8) * 64]);
    } else {
#pragma unroll
      for (int j = 0; j < 4; ++j) {
        f32x4 a = *(const f32x4*)(wfg + kt * 64 + j * 8);
        f32x4 b = *(const f32x4*)(wfg + kt * 64 + j * 8 + 4);
        bf16x8 r;
#pragma unroll
        for (int e = 0; e < 4; ++e) {
          r[e] = (bf16_t)a[e];
          r[4 + e] = (bf16_t)b[e];
        }
        const int slot = (bchunk * 4 + j) ^ (bsrow & 7);
        *(bf16x8*)&Bs[bsrow * 64 + slot * 8] = r;
      }
    }
    __syncthreads();  // drains vmcnt+lgkm: tile resident & published

    // compute: 2 k-halves x 16 MFMA, swizzled conflict-free frag reads
#pragma unroll
    for (int ks = 0; ks < 2; ++ks) {
      bf16x8 af[4], bfr[4];
#pragma unroll
      for (int t = 0; t < 4; ++t) {
        const int ar = wm * 64 + t * 16 + l16;
        const int br = wn * 64 + t * 16 + l16;
        const int slot = ((ks * 4 + quad) ^ (l16 & 7)) * 8;
        af[t] = *(const bf16x8*)&As[ar * 64 + slot];
        bfr[t] = *(const bf16x8*)&Bs[br * 64 + slot];
      }
      __builtin_amdgcn_s_setprio(1);
#pragma unroll
      for (int mi = 0; mi < 4; ++mi)
#pragma unroll
        for (int ni = 0; ni < 4; ++ni)
          acc[mi][ni] = MFMA16(af[mi], bfr[ni], acc[mi][ni]);
      __builtin_amdgcn_s_setprio(0);
    }
  }

#pragma unroll
  for (int ni = 0; ni < 4; ++ni) {
    const int col = n0 + wn * 64 + ni * 16 + l16;
    const float bv = BIAS ? bias[col] : 0.0f;
#pragma unroll
    for (int mi = 0; mi < 4; ++mi) {
      const int row = m0 + wm * 64 + mi * 16 + quad * 4;
#pragma unroll
      for (int r = 0; r < 4; ++r)
        C[(size_t)(row + r) * ldc + col] = (TC)(acc[mi][ni][r] + bv);
    }
  }
}

// ---------------------------------------------------------------------------
// Flash attention (causal), qkv interleaved [B*T, 3C] bf16 (q|k|v).
// Output overwrites the Q slot in place. UNCHANGED from r8 (87.5 µs; pinned
// at ~87.5 across 7 structural variants -> accepted as its floor).
// KVBLK=128, pairing grid (8, B*H), swapped QK^T, exp2-domain softmax,
// diagonal-only mask + wave-uniform ntlim, exact defer-skip, T14 prefetch.
// ---------------------------------------------------------------------------
__global__ __launch_bounds__(512, 4) void attn_mfma(bf16_t* __restrict__ qkv) {
  constexpr int T = 2048, C3 = 3072, C = 1024;
  __shared__ bf16_t Ks[128 * 72];      // [token][d], +8 pad
  __shared__ bf16_t Vt[64 * 136];      // [d][token], +8 pad
  __shared__ bf16_t Ps[8 * 16 * 136];  // per-wave P tile [qrow][key]

  const int tid = threadIdx.x;
  const int wave = tid >> 6;        // 0..7
  const int lane = tid & 63;
  const int l16 = tid & 15;
  const int quad = (tid >> 4) & 3;
  const int p = blockIdx.x;         // 0..7 -> strips p and 15-p
  const int b = blockIdx.y >> 4;
  const int h = blockIdx.y & 15;
  bf16_t* base = qkv + (size_t)b * T * C3;

  const float QSCALE = 0.125f * 1.44269504088896340736f;

  const int krow = wave * 32 + (lane >> 1);
  const int kcol = (lane & 1) * 32;
  const int wv = wave - 4;
  const int vtok = ((wv & 2) << 5) + lane;
  const int vd0 = (wv & 1) * 32;

  bf16_t* pw = &Ps[wave * 16 * 136];

  bf16x8 st0, st1, st2, st3;

  for (int s = 0; s < 2; ++s) {
    const int qt = (s == 0) ? p : 15 - p;
    const int Q0 = qt * 128;
    const int qlo = Q0 + wave * 16;

    bf16x8 qf[2];
    {
      const bf16_t* qp = base + (size_t)(qlo + l16) * C3 + h * 64 + quad * 8;
      bf16x8 a = *(const bf16x8*)qp;
      bf16x8 c = *(const bf16x8*)(qp + 32);
#pragma unroll
      for (int e = 0; e < 8; ++e) {
        a[e] = (bf16_t)((float)a[e] * QSCALE);
        c[e] = (bf16_t)((float)c[e] * QSCALE);
      }
      qf[0] = a;
      qf[1] = c;
    }

    f32x4 Of[4] = {};
    float mrow = -1e30f;
    float lrow = 0.f;

    if (wave < 4) {
      const bf16_t* kp = base + (size_t)krow * C3 + C + h * 64 + kcol;
      st0 = *(const bf16x8*)kp;
      st1 = *(const bf16x8*)(kp + 8);
      st2 = *(const bf16x8*)(kp + 16);
      st3 = *(const bf16x8*)(kp + 24);
    } else {
      const bf16_t* vp = base + (size_t)vtok * C3 + 2 * C + h * 64 + vd0;
      st0 = *(const bf16x8*)vp;
      st1 = *(const bf16x8*)(vp + 8);
      st2 = *(const bf16x8*)(vp + 16);
      st3 = *(const bf16x8*)(vp + 24);
    }

    for (int j0 = 0; j0 <= Q0; j0 += 128) {
      __syncthreads();
      if (wave < 4) {
        *(bf16x8*)&Ks[krow * 72 + kcol] = st0;
        *(bf16x8*)&Ks[krow * 72 + kcol + 8] = st1;
        *(bf16x8*)&Ks[krow * 72 + kcol + 16] = st2;
        *(bf16x8*)&Ks[krow * 72 + kcol + 24] = st3;
      } else {
#pragma unroll
        for (int e = 0; e < 8; ++e) {
          Vt[(vd0 + e) * 136 + vtok] = st0[e];
          Vt[(vd0 + 8 + e) * 136 + vtok] = st1[e];
          Vt[(vd0 + 16 + e) * 136 + vtok] = st2[e];
          Vt[(vd0 + 24 + e) * 136 + vtok] = st3[e];
        }
      }
      if (j0 + 128 <= Q0) {
        const int jn = j0 + 128;
        if (wave < 4) {
          const bf16_t* kp =
              base + (size_t)(jn + krow) * C3 + C + h * 64 + kcol;
          st0 = *(const bf16x8*)kp;
          st1 = *(const bf16x8*)(kp + 8);
          st2 = *(const bf16x8*)(kp + 16);
          st3 = *(const bf16x8*)(kp + 24);
        } else {
          const bf16_t* vp =
              base + (size_t)(jn + vtok) * C3 + 2 * C + h * 64 + vd0;
          st0 = *(const bf16x8*)vp;
          st1 = *(const bf16x8*)(vp + 8);
          st2 = *(const bf16x8*)(vp + 16);
          st3 = *(const bf16x8*)(vp + 24);
        }
      }
      __syncthreads();

      float Sv[8][4];
      int ntlim = 8;
      if (j0 + 128 <= qlo) {
        __builtin_amdgcn_s_setprio(1);
#pragma unroll
        for (int nt = 0; nt < 8; ++nt) {
          f32x4 sacc = {};
#pragma unroll
          for (int s2 = 0; s2 < 2; ++s2) {
            bf16x8 kf = *(const bf16x8*)&Ks[(nt * 16 + l16) * 72 + s2 * 32 +
                                            quad * 8];
            sacc = MFMA16(kf, qf[s2], sacc);
          }
#pragma unroll
          for (int r = 0; r < 4; ++r) Sv[nt][r] = sacc[r];
        }
        __builtin_amdgcn_s_setprio(0);
      } else {
        ntlim = ((qlo + 15 - j0) >> 4) + 1;
        const int qrow = qlo + l16;
        __builtin_amdgcn_s_setprio(1);
#pragma unroll
        for (int nt = 0; nt < 8; ++nt) {
          if (nt < ntlim) {
            f32x4 sacc = {};
#pragma unroll
            for (int s2 = 0; s2 < 2; ++s2) {
              bf16x8 kf = *(const bf16x8*)&Ks[(nt * 16 + l16) * 72 + s2 * 32 +
                                              quad * 8];
              sacc = MFMA16(kf, qf[s2], sacc);
            }
            const int keyb = j0 + nt * 16 + quad * 4;
#pragma unroll
            for (int r = 0; r < 4; ++r)
              Sv[nt][r] = (keyb + r > qrow) ? -1e30f : sacc[r];
          } else {
#pragma unroll
            for (int r = 0; r < 4; ++r) Sv[nt][r] = -1e30f;
          }
        }
        __builtin_amdgcn_s_setprio(0);
      }

      float v = -1e30f;
#pragma unroll
      for (int nt = 0; nt < 8; ++nt)
        v = fmaxf(v, fmaxf(fmaxf(Sv[nt][0], Sv[nt][1]),
                           fmaxf(Sv[nt][2], Sv[nt][3])));
      v = fmaxf(v, __shfl_xor(v, 16));
      v = fmaxf(v, __shfl_xor(v, 32));

      if (__any(v > mrow)) {
        const float mnew = fmaxf(mrow, v);
        const float alpha = __builtin_amdgcn_exp2f(mrow - mnew);
        mrow = mnew;
        lrow *= alpha;
        float ar[4];
#pragma unroll
        for (int r = 0; r < 4; ++r) ar[r] = __shfl(alpha, quad * 4 + r, 16);
#pragma unroll
        for (int dt = 0; dt < 4; ++dt)
#pragma unroll
          for (int r = 0; r < 4; ++r) Of[dt][r] *= ar[r];
      }

      float rs = 0.f;
#pragma unroll
      for (int nt = 0; nt < 8; ++nt) {
        bf16x4 pk;
        float r0 = __builtin_amdgcn_exp2f(Sv[nt][0] - mrow);
        float r1 = __builtin_amdgcn_exp2f(Sv[nt][1] - mrow);
        float r2 = __builtin_amdgcn_exp2f(Sv[nt][2] - mrow);
        float r3 = __builtin_amdgcn_exp2f(Sv[nt][3] - mrow);
        pk[0] = (bf16_t)r0;
        pk[1] = (bf16_t)r1;
        pk[2] = (bf16_t)r2;
        pk[3] = (bf16_t)r3;
        rs += (r0 + r1) + (r2 + r3);
        *(bf16x4*)&pw[l16 * 136 + nt * 16 + quad * 4] = pk;
      }
      rs += __shfl_xor(rs, 16);
      rs += __shfl_xor(rs, 32);
      lrow += rs;

      const int kslim = (ntlim + 1) >> 1;
      bf16x8 pf[4];
#pragma unroll
      for (int ks = 0; ks < 4; ++ks)
        pf[ks] = *(const bf16x8*)&pw[l16 * 136 + ks * 32 + quad * 8];
      __builtin_amdgcn_s_setprio(1);
#pragma unroll
      for (int ks = 0; ks < 4; ++ks) {
        if (ks < kslim) {
#pragma unroll
          for (int dt = 0; dt < 4; ++dt) {
            bf16x8 vf = *(const bf16x8*)&Vt[(dt * 16 + l16) * 136 + ks * 32 +
                                            quad * 8];
            Of[dt] = MFMA16(pf[ks], vf, Of[dt]);
          }
        }
      }
      __builtin_amdgcn_s_setprio(0);
    }

    float lr[4];
#pragma unroll
    for (int r = 0; r < 4; ++r) lr[r] = __shfl(lrow, quad * 4 + r, 16);
    const int t = Q0 + wave * 16 + quad * 4;
#pragma unroll
    for (int r = 0; r < 4; ++r) {
      const float inv = 1.0f / lr[r];
      bf16_t* op = base + (size_t)(t + r) * C3 + h * 64 + l16;
#pragma unroll
      for (int dt = 0; dt < 4; ++dt)
        op[dt * 16] = (bf16_t)(Of[dt][r] * inv);
    }
  }
}

// ---------------------------------------------------------------------------
// I/O contract (R8 probe): ALL inputs f32; output f32.
// ---------------------------------------------------------------------------
extern "C" void kernel_launch(void* const* d_in, const int* in_sizes, int n_in,
                              void* d_out, int out_size, void* d_ws,
                              size_t ws_size, hipStream_t stream) {
  constexpr int B = 4, T = 2048, C = 1024;
  constexpr int M = B * T;  // 8192

  const float* x = (const float*)d_in[0];
  const float* w_qkv = (const float*)d_in[1];
  const float* w_out = (const float*)d_in[2];
  const float* b_out = (const float*)d_in[3];
  for (int i = 0; i < n_in; ++i) {
    const long long s = in_sizes[i];
    if (s == (long long)M * C) x = (const float*)d_in[i];
    else if (s == (long long)3 * C * C) w_qkv = (const float*)d_in[i];
    else if (s == (long long)C * C) w_out = (const float*)d_in[i];
    else if (s == C) b_out = (const float*)d_in[i];
  }

  bf16_t* xb = (bf16_t*)d_out;                    // 16 MB
  bf16_t* wqb = xb + (size_t)M * C;               // 6 MB
  bf16_t* qkv = (bf16_t*)d_ws;                    // 48 MB
  bf16_t* wob = qkv + (size_t)M * 3 * C;          // +2 MB (guarded)
  const bool ws_ok =
      ws_size >= (size_t)M * 3 * C * 2 + (size_t)C * C * 2;

  // single merged cvt launch (x, w_qkv, and w_out if ws allows)
  cvt3_f32_bf16<<<1024, 256, 0, stream>>>(
      x, xb, (long long)M * C, w_qkv, wqb, 3LL * C * C, w_out,
      ws_ok ? wob : nullptr, (long long)C * C);

  // fused QKV: [M,3C] = xb @ wqb^T
  gemm_async<false, bf16_t, false>
      <<<dim3(3 * C / 128, M / 128), 256, 0, stream>>>(
          xb, C, wqb, nullptr, qkv, 3 * C, M, 3 * C, C);

  // attention in place (Q slot of qkv); work-balanced pairing grid
  attn_mfma<<<dim3(8, B * 16), 512, 0, stream>>>(qkv);

  // out = att @ w_out^T + b_out -> f32 d_out
  if (ws_ok)
    gemm_async<false, float, true><<<dim3(C / 128, M / 128), 256, 0, stream>>>(
        qkv, 3 * C, wob, b_out, (float*)d_out, C, M, C, C);
  else
    gemm_async<true, float, true><<<dim3(C / 128, M / 128), 256, 0, stream>>>(
        qkv, 3 * C, w_out, b_out, (float*)d_out, C, M, C, C);
}